// Round 14
// baseline (1289.194 us; speedup 1.0000x reference)
//
#include <hip/hip_runtime.h>
#include <hip/hip_fp16.h>
#include <hip/hip_fp8.h>
#include <math.h>

#define L 1024
#define BATCH 32
#define TS 64
#define PADF 65
#define PADU 66
#define PW 33      // packed u32 words per LDS row (64 fp16 + pad)
#define NT 16
#define NPAIRS 136
#define STEPS 20

struct __align__(8) us4 { unsigned short x, y, z, w; };
struct __align__(4) uc4 { unsigned char x, y, z, w; };
typedef float vf4 __attribute__((ext_vector_type(4)));

__device__ __forceinline__ float4 ld4(const float* p){ return *(const float4*)p; }
__device__ __forceinline__ float4 ld4_nt(const float* p){
  vf4 v = __builtin_nontemporal_load((const vf4*)p);
  float4 r; r.x=v.x; r.y=v.y; r.z=v.z; r.w=v.w; return r;
}
__device__ __forceinline__ void st4_nt(float* p, float a, float b, float c, float d){
  vf4 v; v.x=a; v.y=b; v.z=c; v.w=d;
  __builtin_nontemporal_store(v, (vf4*)p);
}
__device__ __forceinline__ unsigned short f2h(float x){
  __half h = __float2half(x);
  return *(unsigned short*)&h;
}
__device__ __forceinline__ float h2f(unsigned short u){
  __half h; *(unsigned short*)&h = u;
  return __half2float(h);
}
__device__ __forceinline__ float lo16f(unsigned int u){ return h2f((unsigned short)(u & 0xffffu)); }
__device__ __forceinline__ float hi16f(unsigned int u){ return h2f((unsigned short)(u >> 16)); }
__device__ __forceinline__ float exth(unsigned int w, int half){
  return h2f((unsigned short)(w >> (half*16)));
}
__device__ __forceinline__ unsigned int pack2(unsigned short lo, unsigned short hi){
  return (unsigned int)lo | ((unsigned int)hi << 16);
}
__device__ __forceinline__ unsigned char f2q(float x){
  __hip_fp8_e4m3 q(x);
  return (unsigned char)q.__x;
}
__device__ __forceinline__ float q2f(unsigned char u){
  __hip_fp8_e4m3 q;
  q.__x = (__hip_fp8_storage_t)u;
  return (float)q;
}
__device__ __forceinline__ float red16(float v){
  v += __shfl_xor(v, 1); v += __shfl_xor(v, 2);
  v += __shfl_xor(v, 4); v += __shfl_xor(v, 8);
  return v;
}
__device__ __forceinline__ float red8(float v){
  v += __shfl_xor(v, 1); v += __shfl_xor(v, 2);
  v += __shfl_xor(v, 4);
  return v;
}
__device__ __forceinline__ void pair_decode(int p, int& bi, int& bj){
  bi = 0;
  while (p >= NT - bi){ p -= NT - bi; ++bi; }
  bj = bi + p;
}

// pbuf: [0..19] a_t; [20..39] beltc_t (0 for t=0, belt*lrb^(t-1) else); [40] w
__global__ void params_kernel(float* pbuf, const float* w,
                              const float* alpha, const float* belt,
                              const float* lra, const float* lrb) {
  int t = threadIdx.x;
  if (t < STEPS) {
    pbuf[t]         = alpha[0] * powf(lra[0], (float)t);
    pbuf[STEPS + t] = (t == 0) ? 0.f : belt[0] * powf(lrb[0], (float)(t - 1));
  }
  if (t == 0) pbuf[2*STEPS] = w[0];
}

// prep (unchanged from round 13): Sb=fp8(S_bar); Mb=fp16(M); Rh=fp16(rho) (b==0);
// Hh=fp16(scores); rowsum partials of A0 into rs0.
__global__ __launch_bounds__(256, 7)
void prep_kernel(const float* __restrict__ scores, const float* __restrict__ Mm,
                 const float* __restrict__ rho, const float* __restrict__ s,
                 unsigned char* __restrict__ Sb, unsigned short* __restrict__ Mb,
                 unsigned short* __restrict__ Rh, unsigned short* __restrict__ Hh,
                 float* __restrict__ rsOut)
{
  __shared__ float buf1[TS*PADF];
  __shared__ unsigned char buf2[TS*PADU];
  const int b = blockIdx.y;
  int bi, bj; pair_decode(blockIdx.x, bi, bj);
  const bool diag = (bi == bj);
  const int ibase = bi*TS, jbase = bj*TS;
  const int tid = threadIdx.x, cgi = tid & 15, rr = tid >> 4, c4 = cgi*4;
  const size_t bb = (size_t)b << 20;
  const float sv = s[0];

  #pragma unroll
  for (int it = 0; it < 4; ++it){
    int row = it*16 + rr;
    size_t off = bb + ((size_t)(jbase+row)<<10) + ibase + c4;
    float4 v = ld4_nt(scores + off);
    float* d = &buf1[row*PADF + c4];
    d[0]=v.x; d[1]=v.y; d[2]=v.z; d[3]=v.w;
    us4 ho = {f2h(v.x),f2h(v.y),f2h(v.z),f2h(v.w)};
    *(us4*)(Hh + off) = ho;
  }
  __syncthreads();

  #pragma unroll
  for (int it = 0; it < 4; ++it){
    int ii = it*16 + rr;
    size_t offr = ((size_t)(ibase+ii)<<10) + jbase + c4;
    size_t off = bb + offr;
    float4 s4 = ld4_nt(scores + off);
    float4 m4 = ld4_nt(Mm + off);
    if (b == 0){
      float4 r4 = ld4_nt(rho + offr);
      us4 ro = {f2h(r4.x),f2h(r4.y),f2h(r4.z),f2h(r4.w)};
      *(us4*)(Rh + offr) = ro;
    }
    float sc[4] = {s4.x,s4.y,s4.z,s4.w};
    float m [4] = {m4.x,m4.y,m4.z,m4.w};
    unsigned char qs[4];
    unsigned short qm[4], qh[4];
    float part = 0.f;
    #pragma unroll
    for (int k = 0; k < 4; ++k){
      float scT = buf1[(c4+k)*PADF + ii];
      float sbv = 0.5f*(sc[k] + scT) - sv;
      unsigned char q = f2q(sbv);
      buf2[ii*PADU + c4 + k] = q;
      part += (q2f(q) + sv) * m[k];
      qs[k]=q; qm[k]=f2h(m[k]); qh[k]=f2h(sc[k]);
    }
    uc4 so = {qs[0],qs[1],qs[2],qs[3]}; *(uc4*)(Sb + off) = so;
    us4 mo = {qm[0],qm[1],qm[2],qm[3]}; *(us4*)(Mb + off) = mo;
    us4 ho = {qh[0],qh[1],qh[2],qh[3]}; *(us4*)(Hh + off) = ho;
    part = red16(part);
    if (cgi == 0) rsOut[((size_t)(b*NT + bj)<<10) + ibase + ii] = part;
  }
  __syncthreads();

  if (!diag){
    #pragma unroll
    for (int it = 0; it < 4; ++it){
      int jj = it*16 + rr;
      size_t offr = ((size_t)(jbase+jj)<<10) + ibase + c4;
      size_t off = bb + offr;
      float4 m4 = ld4_nt(Mm + off);
      if (b == 0){
        float4 r4 = ld4_nt(rho + offr);
        us4 ro = {f2h(r4.x),f2h(r4.y),f2h(r4.z),f2h(r4.w)};
        *(us4*)(Rh + offr) = ro;
      }
      float m[4] = {m4.x,m4.y,m4.z,m4.w};
      unsigned char qs[4];
      unsigned short qm[4];
      float part = 0.f;
      #pragma unroll
      for (int k = 0; k < 4; ++k){
        unsigned char q = buf2[(c4+k)*PADU + jj];
        part += (q2f(q) + sv) * m[k];
        qs[k]=q; qm[k]=f2h(m[k]);
      }
      uc4 so = {qs[0],qs[1],qs[2],qs[3]}; *(uc4*)(Sb + off) = so;
      us4 mo = {qm[0],qm[1],qm[2],qm[3]}; *(us4*)(Mb + off) = mo;
      part = red16(part);
      if (cgi == 0) rsOut[((size_t)(b*NT + bi)<<10) + jbase + jj] = part;
    }
  }
}

// one step, 16B/lane accesses. 8 elems/thread, 2 passes of 32 rows.
// LAST writes f32 A to Aout. LDS: packed fp16 pairs, 33-word row stride.
template<bool LAST>
__global__ __launch_bounds__(256, LAST ? 4 : 7)
void step_kernel(const unsigned char* __restrict__ Sb,
                 const unsigned short* __restrict__ Mb,
                 const unsigned short* __restrict__ Rh,
                 unsigned short* __restrict__ Hh,
                 const float* __restrict__ rsIn, float* __restrict__ rsOut,
                 const float* __restrict__ LmIn, float* __restrict__ LmOut,
                 const float* __restrict__ pbuf,
                 float* __restrict__ Aout, const int t)
{
  __shared__ unsigned int bufP[TS*PW];   // Hn_ij packed fp16 pairs
  __shared__ unsigned int bufQ[TS*PW];   // Hn_ji packed fp16 pairs
  __shared__ float cbuf[2*TS];

  const int b = blockIdx.y;
  int bi, bj; pair_decode(blockIdx.x, bi, bj);
  const bool diag = (bi == bj);
  const int ibase = bi*TS, jbase = bj*TS;
  const int tid = threadIdx.x;
  const int cgi = tid & 7;      // column group (8 groups of 8 elems)
  const int rw  = tid >> 3;     // row within 32-row stripe
  const int c8  = cgi * 8;
  const size_t bb = (size_t)b << 20;
  const float a_t = pbuf[t];
  const float beltc = pbuf[STEPS + t];
  const float w_ = pbuf[2*STEPS];

  // ---- c phase ----
  if (tid < 128){
    const int half = tid >> 6, lane = tid & 63;
    const int rowbase = half ? jbase : ibase;
    const float* rp = rsIn + ((size_t)(b*NT)<<10) + rowbase + lane;
    float rs = 0.f;
    #pragma unroll
    for (int pq = 0; pq < NT; ++pq) rs += rp[(size_t)pq << 10];
    const float rowm = rs - 1.0f;
    const float rl = fmaxf(rowm, 0.f);
    const float lm = (t == 0) ? (w_ * rl)
                              : (LmIn[((size_t)b<<10) + rowbase + lane] + beltc * rl);
    const float sg = (rowm > 0.f) ? 1.f : ((rowm < 0.f) ? -1.f : 0.f);
    cbuf[tid] = lm * sg;
    if (!LAST && half == 0) LmOut[((size_t)b<<10) + rowbase + lane] = lm;
  }
  __syncthreads();

  float mR[2][8], part1[2];
  unsigned int wbA[2][4];   // phase-A outputs kept for phase C (LAST)

  // ---- phase A: tile-ij update (2 passes of 32 rows) ----
  #pragma unroll
  for (int it = 0; it < 2; ++it){
    const int ii = it*32 + rw;
    const size_t offr = ((size_t)(ibase+ii)<<10) + jbase + c8;
    const size_t off = bb + offr;
    uint4 hu = *(const uint4*)(Hh + off);
    uint4 mu = *(const uint4*)(Mb + off);
    uint2 su = *(const uint2*)(Sb + off);
    uint4 ru = *(const uint4*)(Rh + offr);
    unsigned int hw[4] = {hu.x,hu.y,hu.z,hu.w};
    unsigned int mw[4] = {mu.x,mu.y,mu.z,mu.w};
    unsigned int sw[2] = {su.x,su.y};
    unsigned int rv[4] = {ru.x,ru.y,ru.z,ru.w};
    const float ci = cbuf[ii];
    float p1 = 0.f;
    #pragma unroll
    for (int q = 0; q < 4; ++q){
      float h0 = lo16f(hw[q]), h1 = hi16f(hw[q]);
      float m0 = lo16f(mw[q]), m1 = hi16f(mw[q]);
      float r0 = lo16f(rv[q]), r1 = hi16f(rv[q]);
      float s0 = q2f((unsigned char)((sw[q>>1] >> ((q&1)*16)) & 0xffu));
      float s1 = q2f((unsigned char)((sw[q>>1] >> ((q&1)*16 + 8)) & 0xffu));
      float g0 = s0 - ci - cbuf[TS + c8 + 2*q];
      float g1 = s1 - ci - cbuf[TS + c8 + 2*q + 1];
      float x0 = fmaf(a_t*h0*m0, g0, h0);
      float x1 = fmaf(a_t*h1*m1, g1, h1);
      x0 = fminf(fmaxf(fabsf(x0) - r0*a_t, 0.f), 1.f);
      x1 = fminf(fmaxf(fabsf(x1) - r1*a_t, 0.f), 1.f);
      unsigned short b0 = f2h(x0), b1 = f2h(x1);
      unsigned int wb = pack2(b0, b1);
      wbA[it][q] = wb;
      bufP[ii*PW + cgi*4 + q] = wb;
      p1 += 0.5f*(h2f(b0)*m0 + h2f(b1)*m1);
      mR[it][2*q] = m0; mR[it][2*q+1] = m1;
    }
    part1[it] = p1;
    if (!LAST){
      uint4 o; o.x=wbA[it][0]; o.y=wbA[it][1]; o.z=wbA[it][2]; o.w=wbA[it][3];
      *(uint4*)(Hh + off) = o;
    }
  }
  __syncthreads();

  // ---- phase B: tile-ji update ----
  if (!diag){
    #pragma unroll
    for (int it = 0; it < 2; ++it){
      const int jj = it*32 + rw;
      const size_t offr = ((size_t)(jbase+jj)<<10) + ibase + c8;
      const size_t off = bb + offr;
      uint4 hu = *(const uint4*)(Hh + off);
      uint4 mu = *(const uint4*)(Mb + off);
      uint2 su = *(const uint2*)(Sb + off);
      uint4 ru = *(const uint4*)(Rh + offr);
      unsigned int hw[4] = {hu.x,hu.y,hu.z,hu.w};
      unsigned int mw[4] = {mu.x,mu.y,mu.z,mu.w};
      unsigned int sw[2] = {su.x,su.y};
      unsigned int rv[4] = {ru.x,ru.y,ru.z,ru.w};
      const float cjj = cbuf[TS + jj];
      const int jh = jj >> 1, jl = jj & 1;
      float part = 0.f;
      float av[8];
      unsigned int wb[4];
      #pragma unroll
      for (int q = 0; q < 4; ++q){
        float h0 = lo16f(hw[q]), h1 = hi16f(hw[q]);
        float m0 = lo16f(mw[q]), m1 = hi16f(mw[q]);
        float r0 = lo16f(rv[q]), r1 = hi16f(rv[q]);
        float s0 = q2f((unsigned char)((sw[q>>1] >> ((q&1)*16)) & 0xffu));
        float s1 = q2f((unsigned char)((sw[q>>1] >> ((q&1)*16 + 8)) & 0xffu));
        float g0 = s0 - cjj - cbuf[c8 + 2*q];
        float g1 = s1 - cjj - cbuf[c8 + 2*q + 1];
        float x0 = fmaf(a_t*h0*m0, g0, h0);
        float x1 = fmaf(a_t*h1*m1, g1, h1);
        x0 = fminf(fmaxf(fabsf(x0) - r0*a_t, 0.f), 1.f);
        x1 = fminf(fmaxf(fabsf(x1) - r1*a_t, 0.f), 1.f);
        unsigned short b0 = f2h(x0), b1 = f2h(x1);
        wb[q] = pack2(b0, b1);
        bufQ[jj*PW + cgi*4 + q] = wb[q];
        float hT0 = exth(bufP[(c8 + 2*q  )*PW + jh], jl);
        float hT1 = exth(bufP[(c8 + 2*q+1)*PW + jh], jl);
        if (LAST){
          av[2*q]   = 0.5f*(x0 + hT0)*m0;
          av[2*q+1] = 0.5f*(x1 + hT1)*m1;
        } else {
          part += 0.5f*((h2f(b0) + hT0)*m0 + (h2f(b1) + hT1)*m1);
        }
      }
      if (LAST){
        st4_nt(Aout + off,     av[0], av[1], av[2], av[3]);
        st4_nt(Aout + off + 4, av[4], av[5], av[6], av[7]);
      } else {
        uint4 o; o.x=wb[0]; o.y=wb[1]; o.z=wb[2]; o.w=wb[3];
        *(uint4*)(Hh + off) = o;
        part = red8(part);
        if (cgi == 0) rsOut[((size_t)(b*NT + bi)<<10) + jbase + jj] = part;
      }
    }
  }
  __syncthreads();

  // ---- phase C: rows-i partials (or final A_ij) ----
  const unsigned int* hs = diag ? bufP : bufQ;
  #pragma unroll
  for (int it = 0; it < 2; ++it){
    const int ii = it*32 + rw;
    const int ih = ii >> 1, il = ii & 1;
    if (LAST){
      float av[8];
      #pragma unroll
      for (int q = 0; q < 4; ++q){
        float hv0 = lo16f(wbA[it][q]), hv1 = hi16f(wbA[it][q]);
        float hT0 = exth(hs[(c8 + 2*q  )*PW + ih], il);
        float hT1 = exth(hs[(c8 + 2*q+1)*PW + ih], il);
        av[2*q]   = 0.5f*(hv0 + hT0)*mR[it][2*q];
        av[2*q+1] = 0.5f*(hv1 + hT1)*mR[it][2*q+1];
      }
      const size_t off = bb + ((size_t)(ibase+ii)<<10) + jbase + c8;
      st4_nt(Aout + off,     av[0], av[1], av[2], av[3]);
      st4_nt(Aout + off + 4, av[4], av[5], av[6], av[7]);
    } else {
      float part = part1[it];
      #pragma unroll
      for (int q = 0; q < 4; ++q){
        float hT0 = exth(hs[(c8 + 2*q  )*PW + ih], il);
        float hT1 = exth(hs[(c8 + 2*q+1)*PW + ih], il);
        part += 0.5f*(hT0*mR[it][2*q] + hT1*mR[it][2*q+1]);
      }
      part = red8(part);
      if (cgi == 0) rsOut[((size_t)(b*NT + bj)<<10) + ibase + ii] = part;
    }
  }
}

extern "C" void kernel_launch(void* const* d_in, const int* in_sizes, int n_in,
                              void* d_out, int out_size, void* d_ws, size_t ws_size,
                              hipStream_t stream) {
  const float* scores = (const float*)d_in[0];
  const float* Mm     = (const float*)d_in[1];
  const float* rho    = (const float*)d_in[2];
  const float* s      = (const float*)d_in[3];
  const float* w      = (const float*)d_in[4];
  const float* alpha  = (const float*)d_in[5];
  const float* belt   = (const float*)d_in[6];
  const float* lra    = (const float*)d_in[7];
  const float* lrb    = (const float*)d_in[8];
  float* Aout = (float*)d_out;

  const size_t SBB = (size_t)BATCH*L*L*1;   // fp8 S_bar, 33.5MB
  const size_t MBB = (size_t)BATCH*L*L*2;   // fp16 M, 67MB
  const size_t HHB = (size_t)BATCH*L*L*2;   // fp16 H, 67MB
  const size_t RHB = (size_t)L*L*2;         // fp16 rho, 2MB
  const size_t RSB = (size_t)BATCH*NT*L*4;  // 2MB
  const size_t LMB = (size_t)BATCH*L*4;     // 128KB

  char* wp = (char*)d_ws;
  size_t off = 0;
  unsigned char*  Sb = (unsigned char*)(wp + off);  off += SBB;
  unsigned short* Mb = (unsigned short*)(wp + off); off += MBB;
  unsigned short* Hh = (unsigned short*)(wp + off); off += HHB;
  unsigned short* Rh = (unsigned short*)(wp + off); off += RHB;
  float* rs0 = (float*)(wp + off); off += RSB;
  float* rs1 = (float*)(wp + off); off += RSB;
  float* lm0 = (float*)(wp + off); off += LMB;
  float* lm1 = (float*)(wp + off); off += LMB;
  float* pbuf = (float*)(wp + off); off += 256;
  if (off > ws_size) return;

  params_kernel<<<1, 64, 0, stream>>>(pbuf, w, alpha, belt, lra, lrb);

  dim3 g2(NPAIRS, BATCH);
  prep_kernel<<<g2, 256, 0, stream>>>(scores, Mm, rho, s, Sb, Mb, Rh, Hh, rs0);
  for (int t = 0; t < STEPS; ++t){
    const float* rsIn = (t & 1) ? rs1 : rs0;
    float* rsOut      = (t & 1) ? rs0 : rs1;
    const float* LmIn = (t & 1) ? lm0 : lm1;
    float* LmOut      = (t & 1) ? lm1 : lm0;
    if (t == STEPS-1)
      step_kernel<true ><<<g2, 256, 0, stream>>>(Sb, Mb, Rh, Hh, rsIn, rsOut, LmIn, LmOut,
                                                 pbuf, Aout, t);
    else
      step_kernel<false><<<g2, 256, 0, stream>>>(Sb, Mb, Rh, Hh, rsIn, rsOut, LmIn, LmOut,
                                                 pbuf, Aout, t);
  }
}